// Round 7
// baseline (61.308 us; speedup 1.0000x reference)
//
#include <hip/hip_runtime.h>

#define KDIM   128
#define NELEM  8388608

typedef __attribute__((ext_vector_type(8)))  short  short8;
typedef __attribute__((ext_vector_type(8)))  __bf16 bf16x8;
typedef __attribute__((ext_vector_type(4)))  float  f32x4;

__device__ inline ushort f2bf(float f) {            // RNE fp32 -> bf16
  unsigned u = __builtin_bit_cast(unsigned, f);
  u += 0x7fffu + ((u >> 16) & 1u);
  return (ushort)(u >> 16);
}
__device__ inline f32x4 mfma16(short8 a, short8 b, f32x4 c) {
  return __builtin_amdgcn_mfma_f32_16x16x32_bf16(
      __builtin_bit_cast(bf16x8, a), __builtin_bit_cast(bf16x8, b), c, 0, 0, 0);
}
__device__ inline void gload16(const void* g, void* l) {
  __builtin_amdgcn_global_load_lds(
      (const __attribute__((address_space(1))) unsigned*)g,
      (__attribute__((address_space(3))) unsigned*)l, 16, 0, 0);
}

// ---- prep: embedding fp32 -> bf16 (K-XOR-swizzled) + per-code -0.5*||e||^2 ----
__global__ void vq_prep(const float* __restrict__ emb, ushort* __restrict__ ebf,
                        float* __restrict__ esqm) {
  int j = blockIdx.x, d = threadIdx.x;              // 1024 x 128
  float v = emb[j * KDIM + d];
  ebf[j * KDIM + (d ^ ((j & 7) << 3))] = f2bf(v);   // elem-XOR == byte ^ ((row&7)<<4)
  float s = v * v;
#pragma unroll
  for (int m = 1; m <= 32; m <<= 1) s += __shfl_xor(s, m);
  __shared__ float w[2];
  if ((threadIdx.x & 63) == 0) w[threadIdx.x >> 6] = s;
  __syncthreads();
  if (threadIdx.x == 0) esqm[j] = -0.5f * (w[0] + w[1]);
}

// ---- A: block = (128 rows, 256-code quarter); single-shot stage, no loop sync ----
__global__ __launch_bounds__(256, 2) void vq_scan(
    const float* __restrict__ lat, const ushort* __restrict__ ebf,
    const float* __restrict__ esqm, float* __restrict__ fsq_g,
    float* __restrict__ lists_g) {
  // LDS: [0,65536) ebuf (codes; mbuf f32[128][33] aliases after compute)
  //      [65536,66560) esqmLds f32[256]
  __shared__ __align__(16) unsigned char smem[66560];
  float* esqmLds = (float*)(smem + 65536);
  float* mbuf    = (float*)(smem);

  const int tid = threadIdx.x;
  const int lane = tid & 63, wid = tid >> 6;
  const int q = blockIdx.x & 3, rb = blockIdx.x >> 2;
  const int gR0 = rb * 128;
  const int n = lane & 15, hi = lane >> 4;

  // single-shot DMA: 64 KB quarter (ebf pre-swizzled; linear copy)
  {
    const char* src = (const char*)ebf + q * 65536 + tid * 16;
    char* dst = (char*)smem + tid * 16;
#pragma unroll
    for (int p = 0; p < 16; ++p) gload16(src + p * 4096, dst + p * 4096);
  }
  if (tid < 64) ((float4*)esqmLds)[tid] = ((const float4*)(esqm + q * 256))[tid];

  // latents -> B-frag registers (hides under DMA); fsq written once (q==0)
  short8 bfr[2][4];
#pragma unroll
  for (int ct = 0; ct < 2; ++ct) {
    const float* rp = lat + (size_t)(gR0 + wid * 32 + ct * 16 + n) * KDIM + hi * 8;
    float s = 0.f;
#pragma unroll
    for (int sfr = 0; sfr < 4; ++sfr) {
      float4 v0 = *(const float4*)(rp + sfr * 32);
      float4 v1 = *(const float4*)(rp + sfr * 32 + 4);
      s += v0.x * v0.x + v0.y * v0.y + v0.z * v0.z + v0.w * v0.w
         + v1.x * v1.x + v1.y * v1.y + v1.z * v1.z + v1.w * v1.w;
      short8 b;
      b[0] = (short)f2bf(v0.x); b[1] = (short)f2bf(v0.y);
      b[2] = (short)f2bf(v0.z); b[3] = (short)f2bf(v0.w);
      b[4] = (short)f2bf(v1.x); b[5] = (short)f2bf(v1.y);
      b[6] = (short)f2bf(v1.z); b[7] = (short)f2bf(v1.w);
      bfr[ct][sfr] = b;
    }
    s += __shfl_xor(s, 16);
    s += __shfl_xor(s, 32);
    if (q == 0 && hi == 0) fsq_g[gR0 + wid * 32 + ct * 16 + n] = s;
  }
  asm volatile("s_waitcnt vmcnt(0)" ::: "memory");   // DMA landed
  __syncthreads();                                   // all portions + esqm visible

  // A-read bases (swizzled): byte = n*256 + [(s*64+hi*16) ^ ((n&7)<<4)] + tp*4096
  const int pb = ((hi ^ (n & 3)) << 4) | (((n >> 2) & 1) << 6);
  const char* aE = (const char*)smem + n * 256 + pb;
  const char* aO = (const char*)smem + n * 256 + (pb ^ 64);

  int cidx[4];
#pragma unroll
  for (int r = 0; r < 4; ++r) cidx[r] = q * 256 + hi * 4 + r;   // global code id

  const float NINF = __builtin_bit_cast(float, 0xFF800000u);
  float top[2][8];
#pragma unroll
  for (int ct = 0; ct < 2; ++ct)
#pragma unroll
    for (int p = 0; p < 8; ++p) top[ct][p] = NINF;
  float kq[2][4];

#pragma unroll
  for (int tp = 0; tp < 16; ++tp) {
    f32x4 e = *(const f32x4*)(esqmLds + tp * 16 + hi * 4);
    f32x4 acc0 = e, acc1 = e;     // init = -0.5*||e||^2 -> final = f.e - ||e||^2/2
#pragma unroll
    for (int s = 0; s < 4; ++s) {
      const char* ab = ((s & 1) ? aO : aE) + tp * 4096 + (s >> 1) * 128;
      short8 a = *(const short8*)ab;
      acc0 = mfma16(a, bfr[0][s], acc0);
      acc1 = mfma16(a, bfr[1][s], acc1);
    }
    float kn[2][4];
#pragma unroll
    for (int r = 0; r < 4; ++r) {
      kn[0][r] = __builtin_bit_cast(float,
          (__builtin_bit_cast(unsigned, acc0[r]) & 0xFFFFFC00u) | (unsigned)cidx[r]);
      kn[1][r] = __builtin_bit_cast(float,
          (__builtin_bit_cast(unsigned, acc1[r]) & 0xFFFFFC00u) | (unsigned)cidx[r]);
      cidx[r] += 16;
    }
    if ((tp & 1) == 0) {
#pragma unroll
      for (int ct = 0; ct < 2; ++ct)
#pragma unroll
        for (int r = 0; r < 4; ++r) kq[ct][r] = kn[ct][r];
    } else {
#pragma unroll
      for (int ct = 0; ct < 2; ++ct) {     // 8-code cell max -> top-8 insert
        float x = fmaxf(fmaxf(kq[ct][0], kq[ct][1]), fmaxf(kq[ct][2], kq[ct][3]));
        float y = fmaxf(fmaxf(kn[ct][0], kn[ct][1]), fmaxf(kn[ct][2], kn[ct][3]));
        float key = fmaxf(x, y);
#pragma unroll
        for (int p = 0; p < 8; ++p) {      // descending top-8, branchless
          float mx = fmaxf(top[ct][p], key);
          key = fminf(top[ct][p], key);
          top[ct][p] = mx;
        }
      }
    }
  }

  __syncthreads();   // all ebuf reads done -> mbuf may overwrite

  // dump: row L gets 4 lists (hi); row stride 33 floats spreads banks
#pragma unroll
  for (int ct = 0; ct < 2; ++ct) {
    const int L = wid * 32 + ct * 16 + n;
    float* dst = mbuf + L * 33 + hi * 8;
    *(f32x4*)(dst + 0) = (f32x4){top[ct][0], top[ct][1], top[ct][2], top[ct][3]};
    *(f32x4*)(dst + 4) = (f32x4){top[ct][4], top[ct][5], top[ct][6], top[ct][7]};
  }
  __syncthreads();

  // merge 4 sorted lists -> quarter top-8 per row; write 32 B/row to lists_g
  if (tid < 128) {
    const float* base = mbuf + tid * 33;
    float hh[4]; int ix[4];
#pragma unroll
    for (int j = 0; j < 4; ++j) { hh[j] = base[j * 8]; ix[j] = 1; }
    float o[8];
#pragma unroll
    for (int s = 0; s < 8; ++s) {
      float sel = fmaxf(fmaxf(hh[0], hh[1]), fmaxf(hh[2], hh[3]));
      o[s] = sel;
#pragma unroll
      for (int j = 0; j < 4; ++j) {
        if (hh[j] == sel) {                 // keys unique (id bits)
          hh[j] = (ix[j] < 8) ? base[j * 8 + ix[j]] : NINF;
          ++ix[j];
        }
      }
    }
    float* dst = lists_g + (size_t)(gR0 + tid) * 32 + q * 8;
    *(float4*)(dst + 0) = make_float4(o[0], o[1], o[2], o[3]);
    *(float4*)(dst + 4) = make_float4(o[4], o[5], o[6], o[7]);
  }
}

// ---- B: merge 4 quarter-lists/row, pick k-th, gather + write + loss ----
__global__ __launch_bounds__(256) void vq_out(
    const float* __restrict__ emb, const int* __restrict__ ksel,
    const float* __restrict__ lists_g, const float* __restrict__ fsq_g,
    float* __restrict__ out, float* __restrict__ partial) {
  __shared__ __align__(16) float lbuf[128 * 33];   // padded: merge reads conflict-free
  __shared__ int selLds[128];
  __shared__ float wLds[4];

  const int tid = threadIdx.x;
  const int lane = tid & 63, wid = tid >> 6;
  const int rB0 = blockIdx.x * 128;
  const float NINF = __builtin_bit_cast(float, 0xFF800000u);

  // stage this block's 128 rows x 32 floats of lists (coalesced) into padded LDS
#pragma unroll
  for (int it = 0; it < 4; ++it) {
    int f4 = tid + it * 256;                 // float4 index, flat float f = 4*f4
    int f = f4 * 4;
    int row = f >> 5, col = f & 31;
    float4 v = *(const float4*)(lists_g + (size_t)rB0 * 32 + f);
    *(float4*)(&lbuf[row * 33 + col]) = v;
  }
  __syncthreads();

  float rl = 0.f;
  if (tid < 128) {
    const int row = rB0 + tid;
    int kk = ksel[row & 7]; kk = kk < 0 ? 0 : (kk > 7 ? 7 : kk);
    const float* base = lbuf + tid * 33;
    float hh[4]; int ix[4];
#pragma unroll
    for (int j = 0; j < 4; ++j) { hh[j] = base[j * 8]; ix[j] = 1; }
    float sel;
    for (int s = 0;; ++s) {
      sel = fmaxf(fmaxf(hh[0], hh[1]), fmaxf(hh[2], hh[3]));
      if (s == kk) break;
#pragma unroll
      for (int j = 0; j < 4; ++j) {
        if (hh[j] == sel) {
          hh[j] = (ix[j] < 8) ? base[j * 8 + ix[j]] : NINF;
          ++ix[j];
        }
      }
    }
    unsigned sb = __builtin_bit_cast(unsigned, sel);
    selLds[tid] = (int)(sb & 1023u);
    // row loss = ||f||^2 - 2*(f.e - ||e||^2/2) = ||q - f||^2
    float val = __builtin_bit_cast(float, sb & 0xFFFFFC00u);
    rl = fsq_g[row] - 2.0f * val;
  }
#pragma unroll
  for (int m = 1; m <= 32; m <<= 1) rl += __shfl_xor(rl, m);
  if (lane == 0) wLds[wid] = rl;
  __syncthreads();
  if (tid == 0) partial[blockIdx.x] = wLds[0] + wLds[1] + wLds[2] + wLds[3];

  // epilogue: gather selected fp32 code rows -> out (coalesced; emb L2-hot)
#pragma unroll
  for (int it = 0; it < 16; ++it) {
    int i = tid + it * 256;
    int row = i >> 5, c4 = i & 31;
    int s2 = selLds[row];
    float4 v = *(const float4*)(emb + (size_t)s2 * KDIM + c4 * 4);
    *(float4*)(out + (size_t)(rB0 + row) * KDIM + c4 * 4) = v;
  }
}

// ---- deterministic loss reduction over 512 block partials ----
__global__ void vq_reduce(const float* __restrict__ p, float* __restrict__ loss) {
  int t = threadIdx.x;
  double s = (double)p[t] + (double)p[t + 256];
#pragma unroll
  for (int m = 1; m <= 32; m <<= 1) s += __shfl_xor(s, m);
  __shared__ double w[4];
  if ((t & 63) == 0) w[t >> 6] = s;
  __syncthreads();
  if (t == 0) loss[0] = (float)((w[0] + w[1] + w[2] + w[3]) * (1.25 / 8388608.0));
}

extern "C" void kernel_launch(void* const* d_in, const int* in_sizes, int n_in,
                              void* d_out, int out_size, void* d_ws, size_t ws_size,
                              hipStream_t stream) {
  const float* lat = (const float*)d_in[0];   // [8192,1024] fp32
  const float* emb = (const float*)d_in[1];   // [1024,128]  fp32
  const int* ksel = (const int*)d_in[2];      // [8] int32
  float* out = (float*)d_out;                 // quantized[8388608] + loss[1]

  ushort* ebf     = (ushort*)d_ws;                       // 262144 B swizzled bf16 codes
  float*  esqm    = (float*)((char*)d_ws + 262144);      // 4096 B  (-0.5*||e||^2)
  float*  fsq_g   = (float*)((char*)d_ws + 266240);      // 262144 B per-row ||f||^2
  float*  lists_g = (float*)((char*)d_ws + 528384);      // 8 MB    per-row 4x8 lists
  float*  partial = (float*)((char*)d_ws + 8916992);     // 2048 B

  vq_prep<<<1024, 128, 0, stream>>>(emb, ebf, esqm);
  vq_scan<<<2048, 256, 0, stream>>>(lat, ebf, esqm, fsq_g, lists_g);
  vq_out<<<512, 256, 0, stream>>>(emb, ksel, lists_g, fsq_g, out, partial);
  vq_reduce<<<1, 256, 0, stream>>>(partial, out + NELEM);
}

// Round 10
// 47.201 us; speedup vs baseline: 1.2989x; 1.2989x over previous
//
#include <hip/hip_runtime.h>

#define KDIM   128
#define NELEM  8388608

typedef __attribute__((ext_vector_type(4))) float f32x4;
typedef __attribute__((ext_vector_type(2))) int   int2v;

__device__ inline f32x4 mfma8(long long a, long long b, f32x4 c) {
  return __builtin_amdgcn_mfma_f32_16x16x32_fp8_fp8(a, b, c, 0, 0, 0);
}
__device__ inline void gload16(const void* g, void* l) {
  __builtin_amdgcn_global_load_lds(
      (const __attribute__((address_space(1))) unsigned*)g,
      (__attribute__((address_space(3))) unsigned*)l, 16, 0, 0);
}
__device__ inline long long pk8(float4 v0, float4 v1) {   // 8 fp32 -> 8 fp8 e4m3 (RNE)
  int lo = __builtin_amdgcn_cvt_pk_fp8_f32(v0.x, v0.y, 0, false);
  lo     = __builtin_amdgcn_cvt_pk_fp8_f32(v0.z, v0.w, lo, true);
  int hi = __builtin_amdgcn_cvt_pk_fp8_f32(v1.x, v1.y, 0, false);
  hi     = __builtin_amdgcn_cvt_pk_fp8_f32(v1.z, v1.w, hi, true);
  int2v t; t.x = lo; t.y = hi;
  return __builtin_bit_cast(long long, t);
}
__device__ inline float packk(float s, int c) {           // code id -> low-10 mantissa bits
  return __builtin_bit_cast(float,
      (__builtin_bit_cast(unsigned, s) & 0xFFFFFC00u) | (unsigned)c);
}
__device__ inline float sumsq(float4 a, float4 b) {
  return a.x*a.x + a.y*a.y + a.z*a.z + a.w*a.w + b.x*b.x + b.y*b.y + b.z*b.z + b.w*b.w;
}
// merge this lane's sorted-desc top8 with lane^msk's (bitonic top-8 of 16)
__device__ inline void merge8(float (&t)[8], int msk) {
  float o[8];
#pragma unroll
  for (int p = 0; p < 8; ++p) o[p] = __shfl_xor(t[p], msk);
  float m[8];
#pragma unroll
  for (int p = 0; p < 8; ++p) m[p] = fmaxf(t[p], o[7 - p]);
#pragma unroll
  for (int s = 4; s; s >>= 1)
#pragma unroll
    for (int i = 0; i < 8; ++i)
      if (!(i & s)) {
        float x = fmaxf(m[i], m[i | s]);
        m[i | s] = fminf(m[i], m[i | s]);
        m[i] = x;
      }
#pragma unroll
  for (int p = 0; p < 8; ++p) t[p] = m[p];
}

// ---- prep: emb -> fp8 (x1024, K-XOR-swizzled) + -512*||e||^2 + zero accumulators ----
__global__ void vq_prep(const float* __restrict__ emb, unsigned char* __restrict__ ebf8,
                        float* __restrict__ esqm, unsigned long long* __restrict__ lossAcc,
                        unsigned* __restrict__ cnt) {
  int j = blockIdx.x, d = threadIdx.x;              // 1024 x 128
  float v = emb[j * KDIM + d];
  float vs = v * 1024.0f;                           // into e4m3 normal range
  int p = __builtin_amdgcn_cvt_pk_fp8_f32(vs, vs, 0, false);
  ebf8[j * KDIM + (d ^ ((j & 15) << 3))] = (unsigned char)(p & 0xFF);
  float s = v * v;
#pragma unroll
  for (int m = 1; m <= 32; m <<= 1) s += __shfl_xor(s, m);
  __shared__ float w[2];
  if ((d & 63) == 0) w[d >> 6] = s;
  __syncthreads();
  if (d == 0) esqm[j] = -512.0f * (w[0] + w[1]);    // acc-init => score = 1024*(f.e - ||e||^2/2)
  if (j == 0 && d == 0) { lossAcc[0] = 0ULL; cnt[0] = 0u; }
}

// scan 1024 LDS-resident codes against one 16-row register fragment set
__device__ inline void scan_codes(const unsigned char* bk0, const unsigned char* bk1,
                                  const unsigned char* bk2, const unsigned char* bk3,
                                  const float* esqmLds, int hi,
                                  long long v0, long long v1, long long v2, long long v3,
                                  float (&top)[8]) {
  int cid = hi * 4;
#pragma unroll 4
  for (int pp = 0; pp < 32; ++pp) {
    const int off = pp * 4096;
    const float* eb = esqmLds + pp * 32 + hi * 4;
    f32x4 a0 = *(const f32x4*)(eb);
    f32x4 a1 = *(const f32x4*)(eb + 16);
    a0 = mfma8(*(const long long*)(bk0 + off), v0, a0);
    a0 = mfma8(*(const long long*)(bk1 + off), v1, a0);
    a0 = mfma8(*(const long long*)(bk2 + off), v2, a0);
    a0 = mfma8(*(const long long*)(bk3 + off), v3, a0);
    a1 = mfma8(*(const long long*)(bk0 + off + 2048), v0, a1);
    a1 = mfma8(*(const long long*)(bk1 + off + 2048), v1, a1);
    a1 = mfma8(*(const long long*)(bk2 + off + 2048), v2, a1);
    a1 = mfma8(*(const long long*)(bk3 + off + 2048), v3, a1);
    float k0 = packk(a0[0], cid + 0),  k1 = packk(a0[1], cid + 1);
    float k2 = packk(a0[2], cid + 2),  k3 = packk(a0[3], cid + 3);
    float k4 = packk(a1[0], cid + 16), k5 = packk(a1[1], cid + 17);
    float k6 = packk(a1[2], cid + 18), k7 = packk(a1[3], cid + 19);
    float x = fmaxf(fmaxf(fmaxf(k0, k1), fmaxf(k2, k3)),
                    fmaxf(fmaxf(k4, k5), fmaxf(k6, k7)));
#pragma unroll
    for (int p = 0; p < 8; ++p) {                   // descending top-8, branchless
      float mx = fmaxf(top[p], x);
      x = fminf(top[p], x);
      top[p] = mx;
    }
    cid += 32;
  }
}

__device__ inline void write_rows(const float* __restrict__ emb, float* __restrict__ outp,
                                  int grow0, int idx, int lane) {
#pragma unroll 4
  for (int r = 0; r < 16; ++r) {
    int s2 = __shfl(idx, r);
    float2 qv = *(const float2*)(emb + (size_t)s2 * KDIM + lane * 2);
    *(float2*)(outp + (size_t)(grow0 + r) * KDIM + lane * 2) = qv;
  }
}

// ---- main: 1 block/CU (512 thr, 8 waves), codebook LDS-resident, 256 rows/block ----
__global__ __launch_bounds__(512, 1) void vq_main(
    const float* __restrict__ lat, const float* __restrict__ emb,
    const int* __restrict__ ksel, const unsigned char* __restrict__ ebf8,
    const float* __restrict__ esqm, float* __restrict__ out,
    unsigned long long* __restrict__ lossAcc, unsigned* __restrict__ cnt,
    float* __restrict__ loss) {
  __shared__ __align__(16) unsigned char smem[131072 + 4096 + 64];
  float* esqmLds = (float*)(smem + 131072);
  float* wLds    = (float*)(smem + 131072 + 4096);

  const int tid = threadIdx.x, lane = tid & 63, wid = tid >> 6;   // wid 0..7
  const int n = lane & 15, hi = lane >> 4;
  const int gR0 = blockIdx.x * 256;

  // (a) pass-0 latent rows (wid*32 + 0..15) -> issue loads
  const float* rp0 = lat + (size_t)(gR0 + wid * 32 + n) * KDIM + hi * 8;
  float4 p0[4], p1[4];
#pragma unroll
  for (int ks = 0; ks < 4; ++ks) {
    p0[ks] = *(const float4*)(rp0 + ks * 32);
    p1[ks] = *(const float4*)(rp0 + ks * 32 + 4);
  }
  // (b) codebook (128 KB) + norms (4 KB) DMA -> LDS (pre-swizzled; linear copy)
  {
    const char* src = (const char*)ebf8 + tid * 16;
    char* dst = (char*)smem + tid * 16;
#pragma unroll
    for (int qq = 0; qq < 16; ++qq) gload16(src + qq * 8192, dst + qq * 8192);
    if (tid < 256) gload16((const char*)esqm + tid * 16, (char*)esqmLds + tid * 16);
  }
  // (c) pass-1 latent rows (wid*32 + 16..31)
  const float* rp1 = rp0 + 16 * KDIM;
  float4 q0[4], q1[4];
#pragma unroll
  for (int ks = 0; ks < 4; ++ks) {
    q0[ks] = *(const float4*)(rp1 + ks * 32);
    q1[ks] = *(const float4*)(rp1 + ks * 32 + 4);
  }
  // (d) pass-0 frags (fp8) + exact ||f||^2
  float fsq0;
  long long b00, b01, b02, b03;
  {
    float s = 0.f;
#pragma unroll
    for (int ks = 0; ks < 4; ++ks) s += sumsq(p0[ks], p1[ks]);
    s += __shfl_xor(s, 16); s += __shfl_xor(s, 32);
    fsq0 = s;
    b00 = pk8(p0[0], p1[0]); b01 = pk8(p0[1], p1[1]);
    b02 = pk8(p0[2], p1[2]); b03 = pk8(p0[3], p1[3]);
  }
  // FULL drain: DMA + all latent loads complete before anyone crosses the barrier
  asm volatile("s_waitcnt vmcnt(0)" ::: "memory");
  __builtin_amdgcn_s_barrier();

  // A-read addressing: byte = row*128 + ((ks*32+hi*8) ^ ((row&15)<<3))
  const unsigned char* ab = smem + n * 128 + ((hi ^ (n & 3)) << 3);
  const int nh = n >> 2;
  const unsigned char* bk0 = ab + ((0 ^ nh) << 5);
  const unsigned char* bk1 = ab + ((1 ^ nh) << 5);
  const unsigned char* bk2 = ab + ((2 ^ nh) << 5);
  const unsigned char* bk3 = ab + ((3 ^ nh) << 5);

  const float NINF = __builtin_bit_cast(float, 0xFF800000u);
  float top0[8], top1[8];
#pragma unroll
  for (int p = 0; p < 8; ++p) { top0[p] = NINF; top1[p] = NINF; }

  // ---- pass 0: rows wid*32 + 0..15 vs all 1024 codes ----
  scan_codes(bk0, bk1, bk2, bk3, esqmLds, hi, b00, b01, b02, b03, top0);

  // pass-1 conversions (loads long complete)
  float fsq1;
  long long b10, b11, b12, b13;
  {
    float s = 0.f;
#pragma unroll
    for (int ks = 0; ks < 4; ++ks) s += sumsq(q0[ks], q1[ks]);
    s += __shfl_xor(s, 16); s += __shfl_xor(s, 32);
    fsq1 = s;
    b10 = pk8(q0[0], q1[0]); b11 = pk8(q0[1], q1[1]);
    b12 = pk8(q0[2], q1[2]); b13 = pk8(q0[3], q1[3]);
  }

  int kk = ksel[lane & 7];                 // row&7 == n&7 == lane&7 for all passes
  kk = kk < 0 ? 0 : (kk > 7 ? 7 : kk);

  // merge + select + write pass-0 rows (stores overlap pass 1)
  merge8(top0, 16); merge8(top0, 32);
  float sel0 = top0[0];
#pragma unroll
  for (int p = 1; p < 8; ++p) sel0 = (kk == p) ? top0[p] : sel0;
  unsigned sb0 = __builtin_bit_cast(unsigned, sel0);
  int idx0 = (int)(sb0 & 1023u);
  float rl0 = fsq0 - __builtin_bit_cast(float, sb0 & 0xFFFFFC00u) * (1.0f / 512.0f);
  write_rows(emb, out, gR0 + wid * 32, idx0, lane);

  // ---- pass 1: rows wid*32 + 16..31 ----
  scan_codes(bk0, bk1, bk2, bk3, esqmLds, hi, b10, b11, b12, b13, top1);
  merge8(top1, 16); merge8(top1, 32);
  float sel1 = top1[0];
#pragma unroll
  for (int p = 1; p < 8; ++p) sel1 = (kk == p) ? top1[p] : sel1;
  unsigned sb1 = __builtin_bit_cast(unsigned, sel1);
  int idx1 = (int)(sb1 & 1023u);
  float rl1 = fsq1 - __builtin_bit_cast(float, sb1 & 0xFFFFFC00u) * (1.0f / 512.0f);
  write_rows(emb, out, gR0 + wid * 32 + 16, idx1, lane);

  // deterministic loss: per-block double sum -> fixed-point int64 atomic;
  // last block converts (integer adds associative -> replay-stable)
  float c = (lane < 16) ? (rl0 + rl1) : 0.f;
#pragma unroll
  for (int m = 1; m <= 32; m <<= 1) c += __shfl_xor(c, m);
  if (lane == 0) wLds[wid] = c;
  __syncthreads();
  if (tid == 0) {
    double bs = 0.0;
#pragma unroll
    for (int w = 0; w < 8; ++w) bs += (double)wLds[w];
    long long iv = (long long)(bs * 1048576.0 + 0.5);
    atomicAdd(lossAcc, (unsigned long long)iv);
    __threadfence();
    unsigned done = atomicAdd(cnt, 1u);
    if (done == 255u) {
      unsigned long long tot = atomicAdd(lossAcc, 0ULL);
      loss[0] = (float)((double)(long long)tot * (1.25 / (1048576.0 * 8388608.0)));
    }
  }
}

extern "C" void kernel_launch(void* const* d_in, const int* in_sizes, int n_in,
                              void* d_out, int out_size, void* d_ws, size_t ws_size,
                              hipStream_t stream) {
  const float* lat = (const float*)d_in[0];   // [8192,1024] fp32
  const float* emb = (const float*)d_in[1];   // [1024,128]  fp32
  const int* ksel = (const int*)d_in[2];      // [8] int32
  float* out = (float*)d_out;                 // quantized[8388608] + loss[1]

  unsigned char* ebf8 = (unsigned char*)d_ws;                 // 131072 B swizzled fp8 codes
  float* esqm = (float*)((char*)d_ws + 131072);               // 4096 B (-512*||e||^2)
  unsigned long long* lossAcc =
      (unsigned long long*)((char*)d_ws + 135168);            // 8 B fixed-point loss
  unsigned* cnt = (unsigned*)((char*)d_ws + 135176);          // 4 B block counter

  vq_prep<<<1024, 128, 0, stream>>>(emb, ebf8, esqm, lossAcc, cnt);
  vq_main<<<256, 512, 0, stream>>>(lat, emb, ksel, ebf8, esqm, out, lossAcc, cnt,
                                   out + NELEM);
}

// Round 11
// 44.196 us; speedup vs baseline: 1.3872x; 1.0680x over previous
//
#include <hip/hip_runtime.h>

#define KDIM   128
#define NELEM  8388608

typedef __attribute__((ext_vector_type(4))) float f32x4;
typedef __attribute__((ext_vector_type(2))) int   int2v;

__device__ inline f32x4 mfma8(long long a, long long b, f32x4 c) {
  return __builtin_amdgcn_mfma_f32_16x16x32_fp8_fp8(a, b, c, 0, 0, 0);
}
__device__ inline void gload16(const void* g, void* l) {
  __builtin_amdgcn_global_load_lds(
      (const __attribute__((address_space(1))) unsigned*)g,
      (__attribute__((address_space(3))) unsigned*)l, 16, 0, 0);
}
__device__ inline long long pk8(float4 v0, float4 v1) {   // 8 fp32 -> 8 fp8 e4m3 (RNE)
  int lo = __builtin_amdgcn_cvt_pk_fp8_f32(v0.x, v0.y, 0, false);
  lo     = __builtin_amdgcn_cvt_pk_fp8_f32(v0.z, v0.w, lo, true);
  int hi = __builtin_amdgcn_cvt_pk_fp8_f32(v1.x, v1.y, 0, false);
  hi     = __builtin_amdgcn_cvt_pk_fp8_f32(v1.z, v1.w, hi, true);
  int2v t; t.x = lo; t.y = hi;
  return __builtin_bit_cast(long long, t);
}
__device__ inline float packk(float s, int c) {           // code id -> low-10 mantissa bits
  return __builtin_bit_cast(float,
      (__builtin_bit_cast(unsigned, s) & 0xFFFFFC00u) | (unsigned)c);
}
__device__ inline float sumsq(float4 a, float4 b) {
  return a.x*a.x + a.y*a.y + a.z*a.z + a.w*a.w + b.x*b.x + b.y*b.y + b.z*b.z + b.w*b.w;
}
// merge this lane's sorted-desc top8 with lane^msk's (bitonic top-8 of 16)
__device__ inline void merge8(float (&t)[8], int msk) {
  float o[8];
#pragma unroll
  for (int p = 0; p < 8; ++p) o[p] = __shfl_xor(t[p], msk);
  float m[8];
#pragma unroll
  for (int p = 0; p < 8; ++p) m[p] = fmaxf(t[p], o[7 - p]);
#pragma unroll
  for (int s = 4; s; s >>= 1)
#pragma unroll
    for (int i = 0; i < 8; ++i)
      if (!(i & s)) {
        float x = fmaxf(m[i], m[i | s]);
        m[i | s] = fminf(m[i], m[i | s]);
        m[i] = x;
      }
#pragma unroll
  for (int p = 0; p < 8; ++p) t[p] = m[p];
}

// ---- prep: emb -> fp8 (x1024, K-XOR-swizzled) + -512*||e||^2 + zero accumulators ----
__global__ void vq_prep(const float* __restrict__ emb, unsigned char* __restrict__ ebf8,
                        float* __restrict__ esqm, unsigned long long* __restrict__ lossAcc,
                        unsigned* __restrict__ cnt) {
  int j = blockIdx.x, d = threadIdx.x;              // 1024 x 128
  float v = emb[j * KDIM + d];
  float vs = v * 1024.0f;                           // into e4m3 normal range
  int p = __builtin_amdgcn_cvt_pk_fp8_f32(vs, vs, 0, false);
  ebf8[j * KDIM + (d ^ ((j & 15) << 3))] = (unsigned char)(p & 0xFF);
  float s = v * v;
#pragma unroll
  for (int m = 1; m <= 32; m <<= 1) s += __shfl_xor(s, m);
  __shared__ float w[2];
  if ((d & 63) == 0) w[d >> 6] = s;
  __syncthreads();
  if (d == 0) esqm[j] = -512.0f * (w[0] + w[1]);    // acc-init => score = 1024*(f.e - ||e||^2/2)
  if (j == 0 && d == 0) { lossAcc[0] = 0ULL; cnt[0] = 0u; }
}

// scan 1024 LDS-resident codes against one 16-row register fragment set;
// two 2-deep MFMA chains per code-group (accA esqm-init, accB zero-init)
__device__ inline void scan_codes(const unsigned char* bk0, const unsigned char* bk1,
                                  const unsigned char* bk2, const unsigned char* bk3,
                                  const float* esqmLds, int hi,
                                  long long v0, long long v1, long long v2, long long v3,
                                  float (&top)[8]) {
  int cid = hi * 4;
#pragma unroll 2
  for (int pp = 0; pp < 32; ++pp) {
    const int off = pp * 4096;
    const float* eb = esqmLds + pp * 32 + hi * 4;
    f32x4 a0 = *(const f32x4*)(eb);
    f32x4 a1 = *(const f32x4*)(eb + 16);
    f32x4 c0 = (f32x4){0.f, 0.f, 0.f, 0.f};
    f32x4 c1 = (f32x4){0.f, 0.f, 0.f, 0.f};
    a0 = mfma8(*(const long long*)(bk0 + off), v0, a0);
    a0 = mfma8(*(const long long*)(bk1 + off), v1, a0);
    c0 = mfma8(*(const long long*)(bk2 + off), v2, c0);
    c0 = mfma8(*(const long long*)(bk3 + off), v3, c0);
    a1 = mfma8(*(const long long*)(bk0 + off + 2048), v0, a1);
    a1 = mfma8(*(const long long*)(bk1 + off + 2048), v1, a1);
    c1 = mfma8(*(const long long*)(bk2 + off + 2048), v2, c1);
    c1 = mfma8(*(const long long*)(bk3 + off + 2048), v3, c1);
    a0 += c0;
    a1 += c1;
    float k0 = packk(a0[0], cid + 0),  k1 = packk(a0[1], cid + 1);
    float k2 = packk(a0[2], cid + 2),  k3 = packk(a0[3], cid + 3);
    float k4 = packk(a1[0], cid + 16), k5 = packk(a1[1], cid + 17);
    float k6 = packk(a1[2], cid + 18), k7 = packk(a1[3], cid + 19);
    float x = fmaxf(fmaxf(fmaxf(k0, k1), fmaxf(k2, k3)),
                    fmaxf(fmaxf(k4, k5), fmaxf(k6, k7)));
#pragma unroll
    for (int p = 0; p < 8; ++p) {                   // descending top-8, branchless
      float mx = fmaxf(top[p], x);
      x = fminf(top[p], x);
      top[p] = mx;
    }
    cid += 32;
  }
}

__device__ inline void write_rows(const float* __restrict__ emb, float* __restrict__ outp,
                                  int grow0, int idx, int lane) {
#pragma unroll 4
  for (int r = 0; r < 16; ++r) {
    int s2 = __shfl(idx, r);
    float2 qv = *(const float2*)(emb + (size_t)s2 * KDIM + lane * 2);
    *(float2*)(outp + (size_t)(grow0 + r) * KDIM + lane * 2) = qv;
  }
}

// ---- main: 1 block/CU (1024 thr, 16 waves = 4/SIMD), codebook LDS-resident ----
__global__ __launch_bounds__(1024, 4) void vq_main(
    const float* __restrict__ lat, const float* __restrict__ emb,
    const int* __restrict__ ksel, const unsigned char* __restrict__ ebf8,
    const float* __restrict__ esqm, float* __restrict__ out,
    unsigned long long* __restrict__ lossAcc, unsigned* __restrict__ cnt,
    float* __restrict__ loss) {
  __shared__ __align__(16) unsigned char smem[131072 + 4096 + 64];
  float* esqmLds = (float*)(smem + 131072);
  float* wLds    = (float*)(smem + 131072 + 4096);

  const int tid = threadIdx.x, lane = tid & 63, wid = tid >> 6;   // wid 0..15
  const int n = lane & 15, hi = lane >> 4;
  const int gR0 = blockIdx.x * 256;

  // (a) this wave's 16 latent rows -> issue loads
  const float* rp0 = lat + (size_t)(gR0 + wid * 16 + n) * KDIM + hi * 8;
  float4 p0[4], p1[4];
#pragma unroll
  for (int ks = 0; ks < 4; ++ks) {
    p0[ks] = *(const float4*)(rp0 + ks * 32);
    p1[ks] = *(const float4*)(rp0 + ks * 32 + 4);
  }
  // (b) codebook (128 KB) + norms (4 KB) DMA -> LDS (pre-swizzled; linear copy)
  {
    const char* src = (const char*)ebf8 + tid * 16;
    char* dst = (char*)smem + tid * 16;
#pragma unroll
    for (int qq = 0; qq < 8; ++qq) gload16(src + qq * 16384, dst + qq * 16384);
    if (tid < 256) gload16((const char*)esqm + tid * 16, (char*)esqmLds + tid * 16);
  }
  // (c) frags (fp8) + exact ||f||^2
  float fsq0;
  long long b00, b01, b02, b03;
  {
    float s = 0.f;
#pragma unroll
    for (int ks = 0; ks < 4; ++ks) s += sumsq(p0[ks], p1[ks]);
    s += __shfl_xor(s, 16); s += __shfl_xor(s, 32);
    fsq0 = s;
    b00 = pk8(p0[0], p1[0]); b01 = pk8(p0[1], p1[1]);
    b02 = pk8(p0[2], p1[2]); b03 = pk8(p0[3], p1[3]);
  }
  // FULL drain: DMA + latent loads complete before anyone crosses the barrier
  asm volatile("s_waitcnt vmcnt(0)" ::: "memory");
  __builtin_amdgcn_s_barrier();

  // A-read addressing: byte = row*128 + ((ks*32+hi*8) ^ ((row&15)<<3))
  const unsigned char* ab = smem + n * 128 + ((hi ^ (n & 3)) << 3);
  const int nh = n >> 2;
  const unsigned char* bk0 = ab + ((0 ^ nh) << 5);
  const unsigned char* bk1 = ab + ((1 ^ nh) << 5);
  const unsigned char* bk2 = ab + ((2 ^ nh) << 5);
  const unsigned char* bk3 = ab + ((3 ^ nh) << 5);

  const float NINF = __builtin_bit_cast(float, 0xFF800000u);
  float top0[8];
#pragma unroll
  for (int p = 0; p < 8; ++p) top0[p] = NINF;

  // ---- scan: rows wid*16 + 0..15 vs all 1024 codes ----
  scan_codes(bk0, bk1, bk2, bk3, esqmLds, hi, b00, b01, b02, b03, top0);

  int kk = ksel[lane & 7];                 // row&7 == n&7 == lane&7
  kk = kk < 0 ? 0 : (kk > 7 ? 7 : kk);

  merge8(top0, 16); merge8(top0, 32);
  float sel0 = top0[0];
#pragma unroll
  for (int p = 1; p < 8; ++p) sel0 = (kk == p) ? top0[p] : sel0;
  unsigned sb0 = __builtin_bit_cast(unsigned, sel0);
  int idx0 = (int)(sb0 & 1023u);
  float rl0 = fsq0 - __builtin_bit_cast(float, sb0 & 0xFFFFFC00u) * (1.0f / 512.0f);
  write_rows(emb, out, gR0 + wid * 16, idx0, lane);

  // deterministic loss: per-block double sum -> fixed-point int64 atomic;
  // last block converts (integer adds associative -> replay-stable)
  float c = (lane < 16) ? rl0 : 0.f;
#pragma unroll
  for (int m = 1; m <= 32; m <<= 1) c += __shfl_xor(c, m);
  if (lane == 0) wLds[wid] = c;
  __syncthreads();
  if (tid == 0) {
    double bs = 0.0;
#pragma unroll
    for (int w = 0; w < 16; ++w) bs += (double)wLds[w];
    long long iv = (long long)(bs * 1048576.0 + 0.5);
    atomicAdd(lossAcc, (unsigned long long)iv);
    __threadfence();
    unsigned done = atomicAdd(cnt, 1u);
    if (done == 255u) {
      unsigned long long tot = atomicAdd(lossAcc, 0ULL);
      loss[0] = (float)((double)(long long)tot * (1.25 / (1048576.0 * 8388608.0)));
    }
  }
}

extern "C" void kernel_launch(void* const* d_in, const int* in_sizes, int n_in,
                              void* d_out, int out_size, void* d_ws, size_t ws_size,
                              hipStream_t stream) {
  const float* lat = (const float*)d_in[0];   // [8192,1024] fp32
  const float* emb = (const float*)d_in[1];   // [1024,128]  fp32
  const int* ksel = (const int*)d_in[2];      // [8] int32
  float* out = (float*)d_out;                 // quantized[8388608] + loss[1]

  unsigned char* ebf8 = (unsigned char*)d_ws;                 // 131072 B swizzled fp8 codes
  float* esqm = (float*)((char*)d_ws + 131072);               // 4096 B (-512*||e||^2)
  unsigned long long* lossAcc =
      (unsigned long long*)((char*)d_ws + 135168);            // 8 B fixed-point loss
  unsigned* cnt = (unsigned*)((char*)d_ws + 135176);          // 4 B block counter

  vq_prep<<<1024, 128, 0, stream>>>(emb, ebf8, esqm, lossAcc, cnt);
  vq_main<<<256, 1024, 0, stream>>>(lat, emb, ksel, ebf8, esqm, out, lossAcc, cnt,
                                    out + NELEM);
}